// Round 9
// baseline (222.162 us; speedup 1.0000x reference)
//
#include <hip/hip_runtime.h>

// out[token][0:64] = relu(W[x[token]][0:64] + b[0:64]) + 1e-5
// x: int32 [4194304], W: f32 [100000][64], b: f32 [64], out: f32 [4194304][64]
//
// Two-kernel XCD-ownership gather (R8 = 221us):
//  K1: each block reads its 2048-token slab (2x int4/thread, coalesced),
//      and scatters PACKED u32 entries (tokOff<<14 | idxInXcd) DIRECTLY to
//      per-(xcd,block) fixed-capacity regions in d_ws using only 8 LDS
//      bucket counters. No histogram/scan/LDS-sort/dump passes (R8 had 5
//      LDS passes; regions are fixed-capacity so contiguity was never
//      needed). Scattered 4B writes hit ~1KB L2-resident region tails.
//  K2: block b serves XCD b%8 (round-robin dispatch, confirmed R6); only
//      touches W rows [xcd*12500,+12500)=3.2MB pinned in that XCD's 4MB L2.
//      No LDS, no syncs: each 16-lane group broadcast-loads its region
//      entries directly (L1-resident lines), 8-deep unroll for MLP.
//      Output stores nontemporal.

typedef float f32x4 __attribute__((ext_vector_type(4)));

#define TPB   2048          // tokens per producer block
#define NXCD  8
#define PAD   512           // region capacity; mean 256, sigma 15 -> 17 sigma
#define ROWS_PER_XCD 12500  // 100000/8 -> 3.2 MB f32 per XCD

__device__ __forceinline__ void gather_one_token(
    const f32x4* __restrict__ W4, const f32x4* __restrict__ b4,
    f32x4* __restrict__ out4, long long tok, int idx)
{
    const f32x4* wr   = &W4[(size_t)idx * 16];
    f32x4*       orow = &out4[(size_t)tok * 16];
    for (int q = 0; q < 16; ++q) {
        f32x4 w = wr[q], bb = b4[q], r;
        #pragma unroll
        for (int c = 0; c < 4; ++c)
            r[c] = fmaxf(w[c] + bb[c], 0.0f) + 1e-5f;
        __builtin_nontemporal_store(r, &orow[q]);
    }
}

__global__ __launch_bounds__(256) void partition_kernel(
    const int* __restrict__ x, int ntok,
    int*          __restrict__ counts,   // [NXCD * nblk]
    unsigned int* __restrict__ pairs,    // [NXCD * nblk * PAD]
    const f32x4* __restrict__ W4,
    const f32x4* __restrict__ b4,
    f32x4* __restrict__ out4)
{
    __shared__ int s_ofs[NXCD];

    const int       tid  = threadIdx.x;
    const int       nblk = gridDim.x;
    const long long base = (long long)blockIdx.x * TPB;
    const int       n    = (int)min((long long)TPB, (long long)ntok - base);

    if (tid < NXCD) s_ofs[tid] = 0;
    __syncthreads();

    if (n == TPB) {
        const int4* xs = (const int4*)(x + base);
        #pragma unroll
        for (int it = 0; it < TPB / 4 / 256; ++it) {
            const int4 v   = xs[tid + it * 256];
            const int  off = (tid + it * 256) * 4;
            const int  e4[4] = { v.x, v.y, v.z, v.w };
            #pragma unroll
            for (int q = 0; q < 4; ++q) {
                const int idx = e4[q];
                const int c   = idx / ROWS_PER_XCD;       // magic-mul
                const int p   = atomicAdd(&s_ofs[c], 1);
                const unsigned int pk =
                    ((unsigned int)(off + q) << 14) |
                    (unsigned int)(idx - c * ROWS_PER_XCD);
                if (p < PAD)
                    pairs[((long long)c * nblk + blockIdx.x) * PAD + p] = pk;
                else                                      // statistically never
                    gather_one_token(W4, b4, out4, base + off + q, idx);
            }
        }
    } else {
        for (int i = tid; i < n; i += 256) {
            const int idx = x[base + i];
            const int c   = idx / ROWS_PER_XCD;
            const int p   = atomicAdd(&s_ofs[c], 1);
            const unsigned int pk =
                ((unsigned int)i << 14) | (unsigned int)(idx - c * ROWS_PER_XCD);
            if (p < PAD)
                pairs[((long long)c * nblk + blockIdx.x) * PAD + p] = pk;
            else
                gather_one_token(W4, b4, out4, base + i, idx);
        }
    }
    __syncthreads();
    if (tid < NXCD)
        counts[(long long)tid * nblk + blockIdx.x] = min(s_ofs[tid], PAD);
}

__global__ __launch_bounds__(256) void gather_kernel(
    const int*          __restrict__ counts,
    const unsigned int* __restrict__ pairs,
    const f32x4* __restrict__ W4,
    const f32x4* __restrict__ b4,
    f32x4* __restrict__ out4,
    int nblk)
{
    const int xcd     = blockIdx.x & (NXCD - 1);
    const int w       = blockIdx.x >> 3;
    const int workers = gridDim.x >> 3;                 // 256
    const int rpw     = (nblk + workers - 1) / workers; // 8

    const int   j     = threadIdx.x & 15;
    const f32x4 bias  = b4[j];
    const int   group = threadIdx.x >> 4;
    const f32x4* __restrict__ Wx = W4 + (size_t)xcd * ROWS_PER_XCD * 16;

    for (int r = 0; r < rpw; ++r) {
        const int pb = w * rpw + r;
        if (pb >= nblk) break;
        const long long rec = (long long)xcd * nblk + pb;
        const int n = counts[rec];                      // uniform -> s_load
        const unsigned int* __restrict__ gp = &pairs[rec * PAD];
        const long long tokbase = (long long)pb * TPB;

        int i = group;
        // 8-deep unroll: 8 independent entry loads, then 8 independent
        // W-gathers in flight (static indices -> registers).
        for (; i + 112 < n; i += 128) {
            unsigned int e[8];
            #pragma unroll
            for (int u = 0; u < 8; ++u) e[u] = gp[i + u * 16];
            f32x4 wv[8];
            #pragma unroll
            for (int u = 0; u < 8; ++u)
                wv[u] = Wx[(size_t)(e[u] & 0x3FFFu) * 16 + j];
            #pragma unroll
            for (int u = 0; u < 8; ++u) {
                f32x4 rr;
                #pragma unroll
                for (int c = 0; c < 4; ++c)
                    rr[c] = fmaxf(wv[u][c] + bias[c], 0.0f) + 1e-5f;
                __builtin_nontemporal_store(
                    rr, &out4[(tokbase + (e[u] >> 14)) * 16 + j]);
            }
        }
        for (; i < n; i += 16) {
            const unsigned int e = gp[i];
            f32x4 wv = Wx[(size_t)(e & 0x3FFFu) * 16 + j];
            f32x4 rr;
            #pragma unroll
            for (int c = 0; c < 4; ++c)
                rr[c] = fmaxf(wv[c] + bias[c], 0.0f) + 1e-5f;
            __builtin_nontemporal_store(
                rr, &out4[(tokbase + (e >> 14)) * 16 + j]);
        }
    }
}

// Fallback: direct gather (R3-style, ~300us) if d_ws is too small.
__global__ __launch_bounds__(256) void direct_kernel(
    const int* __restrict__ x,
    const f32x4* __restrict__ W4,
    const f32x4* __restrict__ b4,
    f32x4* __restrict__ out4,
    int ntok)
{
    const int j = threadIdx.x & 15;
    const f32x4 bias = b4[j];
    const int group   = (blockIdx.x * blockDim.x + threadIdx.x) >> 4;
    const int ngroups = (gridDim.x * blockDim.x) >> 4;
    for (int t = group; t < ntok; t += ngroups) {
        const int idx = x[t];
        f32x4 w = W4[(size_t)idx * 16 + j];
        f32x4 r;
        #pragma unroll
        for (int c = 0; c < 4; ++c)
            r[c] = fmaxf(w[c] + bias[c], 0.0f) + 1e-5f;
        __builtin_nontemporal_store(r, &out4[(size_t)t * 16 + j]);
    }
}

extern "C" void kernel_launch(void* const* d_in, const int* in_sizes, int n_in,
                              void* d_out, int out_size, void* d_ws, size_t ws_size,
                              hipStream_t stream) {
    const int*   x   = (const int*)d_in[0];
    const f32x4* W   = (const f32x4*)d_in[1];
    const f32x4* b   = (const f32x4*)d_in[2];
    f32x4*       out = (f32x4*)d_out;
    const int    ntok = in_sizes[0];                  // 4,194,304

    const int nblk = (ntok + TPB - 1) / TPB;          // 2048

    const size_t counts_bytes = (size_t)NXCD * nblk * sizeof(int);
    const size_t pairs_off    = (counts_bytes + 255) & ~(size_t)255;
    const size_t need         = pairs_off + (size_t)NXCD * nblk * PAD * sizeof(unsigned int);

    if (ws_size >= need) {
        int*          counts = (int*)d_ws;
        unsigned int* pairs  = (unsigned int*)((char*)d_ws + pairs_off);

        partition_kernel<<<nblk, 256, 0, stream>>>(x, ntok, counts, pairs, W, b, out);
        gather_kernel<<<2048, 256, 0, stream>>>(counts, pairs, W, b, out, nblk);
    } else {
        direct_kernel<<<2048, 256, 0, stream>>>(x, W, b, out, ntok);
    }
}